// Round 19
// baseline (449.576 us; speedup 1.0000x reference)
//
#include <hip/hip_runtime.h>

#define NN 100000
#define EE 1600000
#define ETOT (EE + NN)
#define FF 48
#define NEG 0.2f
#define BSH 9
#define BNODES 512
#define NBUK ((NN + BNODES - 1) / BNODES)  // 196
#define TILE 2048
#define G0BLK ((NN + 127) / 128)           // 782 gemm0 blocks
#define HISTBLK 512
#define HROW 64                            // bf16 h row stride (128 B)

__device__ __forceinline__ unsigned short f2bf(float x) {
    unsigned u = __float_as_uint(x);
    u += 0x7FFF + ((u >> 16) & 1);         // RNE
    return (unsigned short)(u >> 16);
}
__device__ __forceinline__ float bf2f(unsigned short b) {
    return __uint_as_float(((unsigned)b) << 16);
}
__device__ __forceinline__ float bflo(unsigned u) {
    return __uint_as_float(u << 16);
}
__device__ __forceinline__ float bfhi(unsigned u) {
    return __uint_as_float(u & 0xffff0000u);
}
__device__ __forceinline__ unsigned pk(unsigned short a, unsigned short b) {
    return (unsigned)a | ((unsigned)b << 16);
}

// ---------------- GEMM + alpha body; input f32 (layer0) or bf16; h stored bf16 ----

template <int K, int KC, int R, bool IN16>
__device__ __forceinline__ void gemm_body(int bid, float* Wl, float* asl, float* adl,
                                          const void* __restrict__ inp,
                                          const float* __restrict__ W,
                                          const float* __restrict__ a_s,
                                          const float* __restrict__ a_d,
                                          unsigned short* __restrict__ h16,
                                          float* __restrict__ as_,
                                          float* __restrict__ ad_) {
    int t = threadIdx.x;
    for (int i = t; i < K * FF / 4; i += 256)
        ((float4*)Wl)[i] = ((const float4*)W)[i];
    if (t < FF) { asl[t] = a_s[t]; adl[t] = a_d[t]; }
    __syncthreads();

    int fg = t & 3;
    int pr = t >> 2;
    int r0 = bid * (64 * R) + pr * R;
    if (r0 >= NN) return;

    constexpr int NC = K / KC;
    constexpr int QC = KC / 4;
    const float4* wl4 = (const float4*)Wl;

    float acc[R][12];
#pragma unroll
    for (int r = 0; r < R; r++)
#pragma unroll
        for (int j = 0; j < 12; j++) acc[r][j] = 0.f;

    for (int c = 0; c < NC; c++) {
        float xs[R][KC];
        if (IN16) {
            const unsigned short* a16 = (const unsigned short*)inp;
#pragma unroll
            for (int r = 0; r < R; r++) {
#pragma unroll
                for (int q = 0; q < KC / 8; q++) {
                    uint4 u = *(const uint4*)(a16 + (size_t)(r0 + r) * K + c * KC + q * 8);
                    xs[r][8 * q + 0] = bflo(u.x); xs[r][8 * q + 1] = bfhi(u.x);
                    xs[r][8 * q + 2] = bflo(u.y); xs[r][8 * q + 3] = bfhi(u.y);
                    xs[r][8 * q + 4] = bflo(u.z); xs[r][8 * q + 5] = bfhi(u.z);
                    xs[r][8 * q + 6] = bflo(u.w); xs[r][8 * q + 7] = bfhi(u.w);
                }
            }
        } else {
            const float4* x4 = (const float4*)inp;
#pragma unroll
            for (int r = 0; r < R; r++) {
#pragma unroll
                for (int q = 0; q < QC; q++) {
                    float4 v = x4[(size_t)(r0 + r) * (K / 4) + c * QC + q];
                    xs[r][4 * q + 0] = v.x; xs[r][4 * q + 1] = v.y;
                    xs[r][4 * q + 2] = v.z; xs[r][4 * q + 3] = v.w;
                }
            }
        }
#pragma unroll
        for (int kk = 0; kk < KC; kk++) {
            const int k = c * KC + kk;
            const float4 w0 = wl4[k * 12 + fg * 3 + 0];
            const float4 w1 = wl4[k * 12 + fg * 3 + 1];
            const float4 w2 = wl4[k * 12 + fg * 3 + 2];
#pragma unroll
            for (int r = 0; r < R; r++) {
                const float xv = xs[r][kk];
                acc[r][0] = fmaf(xv, w0.x, acc[r][0]);
                acc[r][1] = fmaf(xv, w0.y, acc[r][1]);
                acc[r][2] = fmaf(xv, w0.z, acc[r][2]);
                acc[r][3] = fmaf(xv, w0.w, acc[r][3]);
                acc[r][4] = fmaf(xv, w1.x, acc[r][4]);
                acc[r][5] = fmaf(xv, w1.y, acc[r][5]);
                acc[r][6] = fmaf(xv, w1.z, acc[r][6]);
                acc[r][7] = fmaf(xv, w1.w, acc[r][7]);
                acc[r][8] = fmaf(xv, w2.x, acc[r][8]);
                acc[r][9] = fmaf(xv, w2.y, acc[r][9]);
                acc[r][10] = fmaf(xv, w2.z, acc[r][10]);
                acc[r][11] = fmaf(xv, w2.w, acc[r][11]);
            }
        }
    }

#pragma unroll
    for (int r = 0; r < R; r++) {
        uint2* hp = (uint2*)(h16 + (size_t)(r0 + r) * HROW + fg * 12);
        hp[0] = make_uint2(pk(f2bf(acc[r][0]), f2bf(acc[r][1])),
                           pk(f2bf(acc[r][2]), f2bf(acc[r][3])));
        hp[1] = make_uint2(pk(f2bf(acc[r][4]), f2bf(acc[r][5])),
                           pk(f2bf(acc[r][6]), f2bf(acc[r][7])));
        hp[2] = make_uint2(pk(f2bf(acc[r][8]), f2bf(acc[r][9])),
                           pk(f2bf(acc[r][10]), f2bf(acc[r][11])));
    }

    float ps[R], pd[R];
#pragma unroll
    for (int r = 0; r < R; r++) { ps[r] = 0.f; pd[r] = 0.f; }
#pragma unroll
    for (int j = 0; j < 12; j++) {
        float av = asl[fg * 12 + j], dv = adl[fg * 12 + j];
#pragma unroll
        for (int r = 0; r < R; r++) {
            ps[r] = fmaf(acc[r][j], av, ps[r]);
            pd[r] = fmaf(acc[r][j], dv, pd[r]);
        }
    }
#pragma unroll
    for (int r = 0; r < R; r++) {
        ps[r] += __shfl_xor(ps[r], 1); ps[r] += __shfl_xor(ps[r], 2);
        pd[r] += __shfl_xor(pd[r], 1); pd[r] += __shfl_xor(pd[r], 2);
    }
    if (fg == 0) {
#pragma unroll
        for (int r = 0; r < R; r++) {
            as_[r0 + r] = ps[r];
            ad_[r0 + r] = pd[r];
        }
    }
}

// merged: blocks [0, G0BLK) layer-0 gemm; [G0BLK, G0BLK+HISTBLK) bucket histogram
__global__ __launch_bounds__(256) void k_g0_hist(const float* __restrict__ x,
                                                 const float* __restrict__ W0,
                                                 const float* __restrict__ a_s,
                                                 const float* __restrict__ a_d,
                                                 unsigned short* __restrict__ h16,
                                                 float* __restrict__ as_,
                                                 float* __restrict__ ad_,
                                                 const int* __restrict__ ei,
                                                 int* __restrict__ bcnt) {
    __shared__ __align__(16) char smem[(100 * FF + 2 * FF) * 4];
    if (blockIdx.x < G0BLK) {
        float* Wl = (float*)smem;
        float* asl = Wl + 100 * FF;
        float* adl = asl + FF;
        gemm_body<100, 20, 2, false>(blockIdx.x, Wl, asl, adl, x, W0, a_s, a_d,
                                     h16, as_, ad_);
    } else {
        int* hh = (int*)smem;
        int t = threadIdx.x;
        int bid = blockIdx.x - G0BLK;
        hh[t] = 0;
        __syncthreads();
        for (int i = bid * 256 + t; i < ETOT; i += HISTBLK * 256) {
            int dd = (i < EE) ? ei[EE + i] : (i - EE);
            atomicAdd(&hh[dd >> BSH], 1);
        }
        __syncthreads();
        if (hh[t] > 0) atomicAdd(&bcnt[t], hh[t]);
    }
}

// bucketed scatter (R17-identical)
__global__ __launch_bounds__(256) void k_bscatter(const int* __restrict__ ei,
                                                  const int* __restrict__ bcnt,
                                                  int* __restrict__ bpos,
                                                  int2* __restrict__ pairs) {
    __shared__ int hist[256], incl[256], exc[256], curv[256], gb[256], sb[256];
    __shared__ int2 stage[TILE];
    __shared__ int staddr[TILE];
    int t = threadIdx.x;
    int bv = (t < NBUK) ? bcnt[t] : 0;
    sb[t] = bv;
    __syncthreads();
    for (int o = 1; o < 256; o <<= 1) {
        int x = (t >= o) ? sb[t - o] : 0;
        __syncthreads();
        sb[t] += x;
        __syncthreads();
    }
    int bexcl = sb[t] - bv;
    hist[t] = 0;
    __syncthreads();
    int base = blockIdx.x * TILE;
    int s[8], d[8], b[8];
#pragma unroll
    for (int j = 0; j < 8; j++) {
        int i = base + t + j * 256;
        if (i < ETOT) {
            int ss, dd;
            if (i < EE) { ss = ei[i]; dd = ei[EE + i]; }
            else { ss = i - EE; dd = ss; }
            s[j] = ss; d[j] = dd; b[j] = dd >> BSH;
            atomicAdd(&hist[b[j]], 1);
        } else {
            b[j] = -1;
        }
    }
    __syncthreads();
    int hv = hist[t];
    incl[t] = hv;
    __syncthreads();
    for (int o = 1; o < 256; o <<= 1) {
        int x = (t >= o) ? incl[t - o] : 0;
        __syncthreads();
        incl[t] += x;
        __syncthreads();
    }
    int excl = incl[t] - hv;
    exc[t] = excl;
    curv[t] = excl;
    if (hv > 0) gb[t] = bexcl + atomicAdd(&bpos[t], hv);
    __syncthreads();
    int total = incl[255];
#pragma unroll
    for (int j = 0; j < 8; j++) {
        if (b[j] >= 0) {
            int pos = atomicAdd(&curv[b[j]], 1);
            stage[pos] = make_int2(s[j], d[j]);
            staddr[pos] = gb[b[j]] + (pos - exc[b[j]]);
        }
    }
    __syncthreads();
    for (int i = t; i < total; i += 256) pairs[staddr[i]] = stage[i];
}

// one block (512 threads) per bucket (R17-identical)
__global__ __launch_bounds__(512) void k_bfill(const int2* __restrict__ pairs,
                                               const int* __restrict__ bcnt,
                                               int* __restrict__ off,
                                               int* __restrict__ ssrc) {
    __shared__ int cnt[BNODES], cu[BNODES], sb[512];
    int blk = blockIdx.x;
    int t = threadIdx.x;
    int n0 = blk << BSH;
    int bv = (t < NBUK) ? bcnt[t] : 0;
    sb[t] = bv;
    __syncthreads();
    for (int o = 1; o < 512; o <<= 1) {
        int x = (t >= o) ? sb[t - o] : 0;
        __syncthreads();
        sb[t] += x;
        __syncthreads();
    }
    int beg = sb[blk] - bcnt[blk];
    int end = sb[blk];
    __syncthreads();
    cnt[t] = 0;
    __syncthreads();
    for (int i = beg + t; i < end; i += 512) {
        atomicAdd(&cnt[pairs[i].y - n0], 1);
    }
    __syncthreads();
    int v = cnt[t];
    sb[t] = v;
    __syncthreads();
    for (int o = 1; o < 512; o <<= 1) {
        int x = (t >= o) ? sb[t - o] : 0;
        __syncthreads();
        sb[t] += x;
        __syncthreads();
    }
    int excl = sb[t] - v;
    cu[t] = excl;
    if (n0 + t < NN) off[n0 + t] = beg + excl;
    if (blk == 0 && t == 0) off[NN] = ETOT;
    __syncthreads();
    for (int i = beg + t; i < end; i += 512) {
        int2 pr = pairs[i];
        int pos = atomicAdd(&cu[pr.y - n0], 1);
        ssrc[beg + pos] = pr.x;
    }
}

// standalone K=48 gemm (R=4), bf16 input
__global__ __launch_bounds__(256) void k_gemm48(const unsigned short* __restrict__ a16,
                                                const float* __restrict__ W,
                                                const float* __restrict__ a_s,
                                                const float* __restrict__ a_d,
                                                unsigned short* __restrict__ h16,
                                                float* __restrict__ as_,
                                                float* __restrict__ ad_) {
    __shared__ float Wl[48 * FF];
    __shared__ float asl[FF], adl[FF];
    gemm_body<48, 16, 4, true>(blockIdx.x, Wl, asl, adl, a16, W, a_s, a_d,
                               h16, as_, ad_);
}

// ---------------- aggregation: h bf16 (128B rows), scalar ssrc, act out bf16 ----

template <bool LAST>
__global__ __launch_bounds__(256) void k_aggr(const unsigned short* __restrict__ h16,
                                              const float* __restrict__ as_,
                                              const float* __restrict__ ad_,
                                              const int* __restrict__ off,
                                              const int* __restrict__ ssrc,
                                              const float* __restrict__ bias,
                                              float* __restrict__ out,
                                              unsigned short* __restrict__ act16) {
    int wave = threadIdx.x >> 6;
    int lane = threadIdx.x & 63;
    int d = blockIdx.x * 4 + wave;
    if (d >= NN) return;
    int beg = __builtin_amdgcn_readfirstlane(off[d]);
    int end = __builtin_amdgcn_readfirstlane(off[d + 1]);
    int deg = end - beg;
    float add = ad_[d];
    int fW = (lane < FF) ? lane : lane - FF;

    float acc = 0.f, s = 0.f;

    if (deg <= 64) {
        float e = -1e30f;
        if (lane < deg) {
            int src = ssrc[beg + lane];
            float t = as_[src] + add;
            e = (t > 0.f) ? t : NEG * t;
        }
        float m = e;
#pragma unroll
        for (int o = 32; o; o >>= 1) m = fmaxf(m, __shfl_xor(m, o));
        float p = (lane < deg) ? __expf(e - m) : 0.f;
        float sv = p;
#pragma unroll
        for (int o = 32; o; o >>= 1) sv += __shfl_xor(sv, o);
        s = sv;

        unsigned pbits = __float_as_uint(p);
        int degR = (deg + 7) & ~7;
        for (int i = 0; i < degR; i += 8) {
            float pj[8], hv[8];
#pragma unroll
            for (int j = 0; j < 8; j++) {
                // wave-uniform address -> scalar load; clamp pad slots to row 0
                int src_j = (i + j < deg) ? ssrc[beg + i + j] : 0;
                const unsigned short* hrow =
                    h16 + ((size_t)(unsigned)src_j << 6);   // SGPR base
                pj[j] = __uint_as_float(
                    (unsigned)__builtin_amdgcn_readlane((int)pbits, i + j));
                hv[j] = bf2f(hrow[fW]);
            }
#pragma unroll
            for (int j = 0; j < 8; j++) acc = fmaf(pj[j], hv[j], acc);
        }
    } else {
        // general path (never taken for this graph)
        float m = -1e30f;
        for (int i = beg + lane; i < end; i += 64) {
            float t = as_[ssrc[i]] + add;
            t = (t > 0.f) ? t : NEG * t;
            m = fmaxf(m, t);
        }
#pragma unroll
        for (int o = 32; o; o >>= 1) m = fmaxf(m, __shfl_xor(m, o));
        for (int i = beg; i < end; i++) {
            int src = ssrc[i];
            float e = as_[src] + add;
            e = (e > 0.f) ? e : NEG * e;
            float pp = __expf(e - m);
            s += pp;
            if (lane < FF) acc = fmaf(pp, bf2f(h16[(size_t)src * HROW + lane]), acc);
        }
    }

    if (lane < FF) {
        float v = acc / fmaxf(s, 1e-16f) + bias[lane];
        v = (v > 0.f) ? v : (__expf(v) - 1.0f);  // ELU
        if (LAST)
            out[(size_t)d * FF + lane] = v;
        else
            act16[(size_t)d * FF + lane] = f2bf(v);
    }
}

// ---------------- launcher ----------------

static inline size_t alup(size_t x) { return (x + 255) & ~(size_t)255; }

extern "C" void kernel_launch(void* const* d_in, const int* in_sizes, int n_in,
                              void* d_out, int out_size, void* d_ws, size_t ws_size,
                              hipStream_t stream) {
    const float* x = (const float*)d_in[0];
    const int* ei = (const int*)d_in[1];
    const float* W0 = (const float*)d_in[2];
    const float* Wr = (const float*)d_in[3];
    const float* As = (const float*)d_in[4];
    const float* Ad = (const float*)d_in[5];
    const float* B = (const float*)d_in[6];
    float* out = (float*)d_out;

    char* p = (char*)d_ws;
    int* off = (int*)p;      p += alup((NN + 1) * sizeof(int));
    int* bcnt = (int*)p;     p += 1024;
    int* bpos = (int*)p;     p += 1024;
    int2* pairs = (int2*)p;  p += alup((size_t)ETOT * sizeof(int2));
    int* ssrc = (int*)p;     p += alup((size_t)ETOT * sizeof(int) + 256);
    unsigned short* h16 = (unsigned short*)p;
    p += alup((size_t)NN * HROW * sizeof(unsigned short) + 256);
    unsigned short* act16 = (unsigned short*)p;
    p += alup((size_t)NN * FF * sizeof(unsigned short) + 256);
    float* as_ = (float*)p;  p += alup(NN * sizeof(float));
    float* ad_ = (float*)p;  p += alup(NN * sizeof(float));

    hipMemsetAsync(bcnt, 0, 2048, stream);  // bcnt + bpos
    k_g0_hist<<<G0BLK + HISTBLK, 256, 0, stream>>>(x, W0, As, Ad, h16, as_, ad_, ei, bcnt);
    k_bscatter<<<(ETOT + TILE - 1) / TILE, 256, 0, stream>>>(ei, bcnt, bpos, pairs);
    k_bfill<<<NBUK, 512, 0, stream>>>(pairs, bcnt, off, ssrc);

    for (int l = 0; l < 5; l++) {
        if (l > 0) {
            int g = (NN + 255) / 256;  // R=4: 256 rows/block
            k_gemm48<<<g, 256, 0, stream>>>(act16, Wr + (size_t)(l - 1) * 48 * 48,
                                            As + l * 48, Ad + l * 48, h16, as_, ad_);
        }
        if (l == 4)
            k_aggr<true><<<(NN + 3) / 4, 256, 0, stream>>>(h16, as_, ad_, off, ssrc,
                                                           B + l * 48, out, nullptr);
        else
            k_aggr<false><<<(NN + 3) / 4, 256, 0, stream>>>(h16, as_, ad_, off, ssrc,
                                                            B + l * 48, nullptr, act16);
    }
}

// Round 20
// 408.561 us; speedup vs baseline: 1.1004x; 1.1004x over previous
//
#include <hip/hip_runtime.h>

#define NN 100000
#define EE 1600000
#define ETOT (EE + NN)
#define FF 48
#define NEG 0.2f
#define BSH 9
#define BNODES 512
#define NBUK ((NN + BNODES - 1) / BNODES)  // 196
#define TILE 2048
#define G0BLK ((NN + 127) / 128)           // 782 gemm0 blocks
#define HISTBLK 512
#define HROW 64                            // bf16 h row stride (128 B)

__device__ __forceinline__ unsigned short f2bf(float x) {
    unsigned u = __float_as_uint(x);
    u += 0x7FFF + ((u >> 16) & 1);         // RNE
    return (unsigned short)(u >> 16);
}
__device__ __forceinline__ float bf2f(unsigned short b) {
    return __uint_as_float(((unsigned)b) << 16);
}
__device__ __forceinline__ float bflo(unsigned u) {
    return __uint_as_float(u << 16);
}
__device__ __forceinline__ float bfhi(unsigned u) {
    return __uint_as_float(u & 0xffff0000u);
}
__device__ __forceinline__ unsigned pk(unsigned short a, unsigned short b) {
    return (unsigned)a | ((unsigned)b << 16);
}

// ---------------- GEMM + alpha body; input f32 (layer0) or bf16; h stored bf16 ----

template <int K, int KC, int R, bool IN16>
__device__ __forceinline__ void gemm_body(int bid, float* Wl, float* asl, float* adl,
                                          const void* __restrict__ inp,
                                          const float* __restrict__ W,
                                          const float* __restrict__ a_s,
                                          const float* __restrict__ a_d,
                                          unsigned short* __restrict__ h16,
                                          float* __restrict__ as_,
                                          float* __restrict__ ad_) {
    int t = threadIdx.x;
    for (int i = t; i < K * FF / 4; i += 256)
        ((float4*)Wl)[i] = ((const float4*)W)[i];
    if (t < FF) { asl[t] = a_s[t]; adl[t] = a_d[t]; }
    __syncthreads();

    int fg = t & 3;
    int pr = t >> 2;
    int r0 = bid * (64 * R) + pr * R;
    if (r0 >= NN) return;

    constexpr int NC = K / KC;
    constexpr int QC = KC / 4;
    const float4* wl4 = (const float4*)Wl;

    float acc[R][12];
#pragma unroll
    for (int r = 0; r < R; r++)
#pragma unroll
        for (int j = 0; j < 12; j++) acc[r][j] = 0.f;

    for (int c = 0; c < NC; c++) {
        float xs[R][KC];
        if (IN16) {
            const unsigned short* a16 = (const unsigned short*)inp;
#pragma unroll
            for (int r = 0; r < R; r++) {
#pragma unroll
                for (int q = 0; q < KC / 8; q++) {
                    uint4 u = *(const uint4*)(a16 + (size_t)(r0 + r) * K + c * KC + q * 8);
                    xs[r][8 * q + 0] = bflo(u.x); xs[r][8 * q + 1] = bfhi(u.x);
                    xs[r][8 * q + 2] = bflo(u.y); xs[r][8 * q + 3] = bfhi(u.y);
                    xs[r][8 * q + 4] = bflo(u.z); xs[r][8 * q + 5] = bfhi(u.z);
                    xs[r][8 * q + 6] = bflo(u.w); xs[r][8 * q + 7] = bfhi(u.w);
                }
            }
        } else {
            const float4* x4 = (const float4*)inp;
#pragma unroll
            for (int r = 0; r < R; r++) {
#pragma unroll
                for (int q = 0; q < QC; q++) {
                    float4 v = x4[(size_t)(r0 + r) * (K / 4) + c * QC + q];
                    xs[r][4 * q + 0] = v.x; xs[r][4 * q + 1] = v.y;
                    xs[r][4 * q + 2] = v.z; xs[r][4 * q + 3] = v.w;
                }
            }
        }
#pragma unroll
        for (int kk = 0; kk < KC; kk++) {
            const int k = c * KC + kk;
            const float4 w0 = wl4[k * 12 + fg * 3 + 0];
            const float4 w1 = wl4[k * 12 + fg * 3 + 1];
            const float4 w2 = wl4[k * 12 + fg * 3 + 2];
#pragma unroll
            for (int r = 0; r < R; r++) {
                const float xv = xs[r][kk];
                acc[r][0] = fmaf(xv, w0.x, acc[r][0]);
                acc[r][1] = fmaf(xv, w0.y, acc[r][1]);
                acc[r][2] = fmaf(xv, w0.z, acc[r][2]);
                acc[r][3] = fmaf(xv, w0.w, acc[r][3]);
                acc[r][4] = fmaf(xv, w1.x, acc[r][4]);
                acc[r][5] = fmaf(xv, w1.y, acc[r][5]);
                acc[r][6] = fmaf(xv, w1.z, acc[r][6]);
                acc[r][7] = fmaf(xv, w1.w, acc[r][7]);
                acc[r][8] = fmaf(xv, w2.x, acc[r][8]);
                acc[r][9] = fmaf(xv, w2.y, acc[r][9]);
                acc[r][10] = fmaf(xv, w2.z, acc[r][10]);
                acc[r][11] = fmaf(xv, w2.w, acc[r][11]);
            }
        }
    }

#pragma unroll
    for (int r = 0; r < R; r++) {
        uint2* hp = (uint2*)(h16 + (size_t)(r0 + r) * HROW + fg * 12);
        hp[0] = make_uint2(pk(f2bf(acc[r][0]), f2bf(acc[r][1])),
                           pk(f2bf(acc[r][2]), f2bf(acc[r][3])));
        hp[1] = make_uint2(pk(f2bf(acc[r][4]), f2bf(acc[r][5])),
                           pk(f2bf(acc[r][6]), f2bf(acc[r][7])));
        hp[2] = make_uint2(pk(f2bf(acc[r][8]), f2bf(acc[r][9])),
                           pk(f2bf(acc[r][10]), f2bf(acc[r][11])));
    }

    float ps[R], pd[R];
#pragma unroll
    for (int r = 0; r < R; r++) { ps[r] = 0.f; pd[r] = 0.f; }
#pragma unroll
    for (int j = 0; j < 12; j++) {
        float av = asl[fg * 12 + j], dv = adl[fg * 12 + j];
#pragma unroll
        for (int r = 0; r < R; r++) {
            ps[r] = fmaf(acc[r][j], av, ps[r]);
            pd[r] = fmaf(acc[r][j], dv, pd[r]);
        }
    }
#pragma unroll
    for (int r = 0; r < R; r++) {
        ps[r] += __shfl_xor(ps[r], 1); ps[r] += __shfl_xor(ps[r], 2);
        pd[r] += __shfl_xor(pd[r], 1); pd[r] += __shfl_xor(pd[r], 2);
    }
    if (fg == 0) {
#pragma unroll
        for (int r = 0; r < R; r++) {
            as_[r0 + r] = ps[r];
            ad_[r0 + r] = pd[r];
        }
    }
}

// merged: blocks [0, G0BLK) layer-0 gemm; [G0BLK, G0BLK+HISTBLK) bucket histogram
__global__ __launch_bounds__(256) void k_g0_hist(const float* __restrict__ x,
                                                 const float* __restrict__ W0,
                                                 const float* __restrict__ a_s,
                                                 const float* __restrict__ a_d,
                                                 unsigned short* __restrict__ h16,
                                                 float* __restrict__ as_,
                                                 float* __restrict__ ad_,
                                                 const int* __restrict__ ei,
                                                 int* __restrict__ bcnt) {
    __shared__ __align__(16) char smem[(100 * FF + 2 * FF) * 4];
    if (blockIdx.x < G0BLK) {
        float* Wl = (float*)smem;
        float* asl = Wl + 100 * FF;
        float* adl = asl + FF;
        gemm_body<100, 20, 2, false>(blockIdx.x, Wl, asl, adl, x, W0, a_s, a_d,
                                     h16, as_, ad_);
    } else {
        int* hh = (int*)smem;
        int t = threadIdx.x;
        int bid = blockIdx.x - G0BLK;
        hh[t] = 0;
        __syncthreads();
        for (int i = bid * 256 + t; i < ETOT; i += HISTBLK * 256) {
            int dd = (i < EE) ? ei[EE + i] : (i - EE);
            atomicAdd(&hh[dd >> BSH], 1);
        }
        __syncthreads();
        if (hh[t] > 0) atomicAdd(&bcnt[t], hh[t]);
    }
}

// bucketed scatter (R17-identical)
__global__ __launch_bounds__(256) void k_bscatter(const int* __restrict__ ei,
                                                  const int* __restrict__ bcnt,
                                                  int* __restrict__ bpos,
                                                  int2* __restrict__ pairs) {
    __shared__ int hist[256], incl[256], exc[256], curv[256], gb[256], sb[256];
    __shared__ int2 stage[TILE];
    __shared__ int staddr[TILE];
    int t = threadIdx.x;
    int bv = (t < NBUK) ? bcnt[t] : 0;
    sb[t] = bv;
    __syncthreads();
    for (int o = 1; o < 256; o <<= 1) {
        int x = (t >= o) ? sb[t - o] : 0;
        __syncthreads();
        sb[t] += x;
        __syncthreads();
    }
    int bexcl = sb[t] - bv;
    hist[t] = 0;
    __syncthreads();
    int base = blockIdx.x * TILE;
    int s[8], d[8], b[8];
#pragma unroll
    for (int j = 0; j < 8; j++) {
        int i = base + t + j * 256;
        if (i < ETOT) {
            int ss, dd;
            if (i < EE) { ss = ei[i]; dd = ei[EE + i]; }
            else { ss = i - EE; dd = ss; }
            s[j] = ss; d[j] = dd; b[j] = dd >> BSH;
            atomicAdd(&hist[b[j]], 1);
        } else {
            b[j] = -1;
        }
    }
    __syncthreads();
    int hv = hist[t];
    incl[t] = hv;
    __syncthreads();
    for (int o = 1; o < 256; o <<= 1) {
        int x = (t >= o) ? incl[t - o] : 0;
        __syncthreads();
        incl[t] += x;
        __syncthreads();
    }
    int excl = incl[t] - hv;
    exc[t] = excl;
    curv[t] = excl;
    if (hv > 0) gb[t] = bexcl + atomicAdd(&bpos[t], hv);
    __syncthreads();
    int total = incl[255];
#pragma unroll
    for (int j = 0; j < 8; j++) {
        if (b[j] >= 0) {
            int pos = atomicAdd(&curv[b[j]], 1);
            stage[pos] = make_int2(s[j], d[j]);
            staddr[pos] = gb[b[j]] + (pos - exc[b[j]]);
        }
    }
    __syncthreads();
    for (int i = t; i < total; i += 256) pairs[staddr[i]] = stage[i];
}

// one block (512 threads) per bucket (R17-identical)
__global__ __launch_bounds__(512) void k_bfill(const int2* __restrict__ pairs,
                                               const int* __restrict__ bcnt,
                                               int* __restrict__ off,
                                               int* __restrict__ ssrc) {
    __shared__ int cnt[BNODES], cu[BNODES], sb[512];
    int blk = blockIdx.x;
    int t = threadIdx.x;
    int n0 = blk << BSH;
    int bv = (t < NBUK) ? bcnt[t] : 0;
    sb[t] = bv;
    __syncthreads();
    for (int o = 1; o < 512; o <<= 1) {
        int x = (t >= o) ? sb[t - o] : 0;
        __syncthreads();
        sb[t] += x;
        __syncthreads();
    }
    int beg = sb[blk] - bcnt[blk];
    int end = sb[blk];
    __syncthreads();
    cnt[t] = 0;
    __syncthreads();
    for (int i = beg + t; i < end; i += 512) {
        atomicAdd(&cnt[pairs[i].y - n0], 1);
    }
    __syncthreads();
    int v = cnt[t];
    sb[t] = v;
    __syncthreads();
    for (int o = 1; o < 512; o <<= 1) {
        int x = (t >= o) ? sb[t - o] : 0;
        __syncthreads();
        sb[t] += x;
        __syncthreads();
    }
    int excl = sb[t] - v;
    cu[t] = excl;
    if (n0 + t < NN) off[n0 + t] = beg + excl;
    if (blk == 0 && t == 0) off[NN] = ETOT;
    __syncthreads();
    for (int i = beg + t; i < end; i += 512) {
        int2 pr = pairs[i];
        int pos = atomicAdd(&cu[pr.y - n0], 1);
        ssrc[beg + pos] = pr.x;
    }
}

// standalone K=48 gemm (R=4), bf16 input
__global__ __launch_bounds__(256) void k_gemm48(const unsigned short* __restrict__ a16,
                                                const float* __restrict__ W,
                                                const float* __restrict__ a_s,
                                                const float* __restrict__ a_d,
                                                unsigned short* __restrict__ h16,
                                                float* __restrict__ as_,
                                                float* __restrict__ ad_) {
    __shared__ float Wl[48 * FF];
    __shared__ float asl[FF], adl[FF];
    gemm_body<48, 16, 4, true>(blockIdx.x, Wl, asl, adl, a16, W, a_s, a_d,
                               h16, as_, ad_);
}

// ---------------- aggregation: h bf16 (128B rows), R18 readlane gather,
// act out bf16 ----

template <bool LAST>
__global__ __launch_bounds__(256) void k_aggr(const unsigned short* __restrict__ h16,
                                              const float* __restrict__ as_,
                                              const float* __restrict__ ad_,
                                              const int* __restrict__ off,
                                              const int* __restrict__ ssrc,
                                              const float* __restrict__ bias,
                                              float* __restrict__ out,
                                              unsigned short* __restrict__ act16) {
    int wave = threadIdx.x >> 6;
    int lane = threadIdx.x & 63;
    int d = blockIdx.x * 4 + wave;
    if (d >= NN) return;
    int beg = __builtin_amdgcn_readfirstlane(off[d]);
    int end = __builtin_amdgcn_readfirstlane(off[d + 1]);
    int deg = end - beg;
    float add = ad_[d];
    int fW = (lane < FF) ? lane : lane - FF;
    unsigned foff = (unsigned)(fW * 2);
    const char* hb = (const char*)h16;

    float acc = 0.f, s = 0.f;

    if (deg <= 64) {
        int srcb = 0;
        float e = -1e30f;
        if (lane < deg) {
            int src = ssrc[beg + lane];
            srcb = src << 7;               // 128 B rows
            float t = as_[src] + add;
            e = (t > 0.f) ? t : NEG * t;
        }
        float m = e;
#pragma unroll
        for (int o = 32; o; o >>= 1) m = fmaxf(m, __shfl_xor(m, o));
        float p = (lane < deg) ? __expf(e - m) : 0.f;
        float sv = p;
#pragma unroll
        for (int o = 32; o; o >>= 1) sv += __shfl_xor(sv, o);
        s = sv;

        unsigned pbits = __float_as_uint(p);
        int degR = (deg + 7) & ~7;
        for (int i = 0; i < degR; i += 8) {
            float pj[8], hv[8];
#pragma unroll
            for (int j = 0; j < 8; j++) {
                pj[j] = __uint_as_float(
                    (unsigned)__builtin_amdgcn_readlane((int)pbits, i + j));
                int sbj = __builtin_amdgcn_readlane(srcb, i + j);
                hv[j] = bf2f(*(const unsigned short*)(hb + (unsigned)sbj + foff));
            }
#pragma unroll
            for (int j = 0; j < 8; j++) acc = fmaf(pj[j], hv[j], acc);
        }
    } else {
        // general path (never taken for this graph)
        float m = -1e30f;
        for (int i = beg + lane; i < end; i += 64) {
            float t = as_[ssrc[i]] + add;
            t = (t > 0.f) ? t : NEG * t;
            m = fmaxf(m, t);
        }
#pragma unroll
        for (int o = 32; o; o >>= 1) m = fmaxf(m, __shfl_xor(m, o));
        for (int i = beg; i < end; i++) {
            int src = ssrc[i];
            float e = as_[src] + add;
            e = (e > 0.f) ? e : NEG * e;
            float pp = __expf(e - m);
            s += pp;
            if (lane < FF) acc = fmaf(pp, bf2f(h16[(size_t)src * HROW + lane]), acc);
        }
    }

    if (lane < FF) {
        float v = acc / fmaxf(s, 1e-16f) + bias[lane];
        v = (v > 0.f) ? v : (__expf(v) - 1.0f);  // ELU
        if (LAST)
            out[(size_t)d * FF + lane] = v;
        else
            act16[(size_t)d * FF + lane] = f2bf(v);
    }
}

// ---------------- launcher ----------------

static inline size_t alup(size_t x) { return (x + 255) & ~(size_t)255; }

extern "C" void kernel_launch(void* const* d_in, const int* in_sizes, int n_in,
                              void* d_out, int out_size, void* d_ws, size_t ws_size,
                              hipStream_t stream) {
    const float* x = (const float*)d_in[0];
    const int* ei = (const int*)d_in[1];
    const float* W0 = (const float*)d_in[2];
    const float* Wr = (const float*)d_in[3];
    const float* As = (const float*)d_in[4];
    const float* Ad = (const float*)d_in[5];
    const float* B = (const float*)d_in[6];
    float* out = (float*)d_out;

    char* p = (char*)d_ws;
    int* off = (int*)p;      p += alup((NN + 1) * sizeof(int));
    int* bcnt = (int*)p;     p += 1024;
    int* bpos = (int*)p;     p += 1024;
    int2* pairs = (int2*)p;  p += alup((size_t)ETOT * sizeof(int2));
    int* ssrc = (int*)p;     p += alup((size_t)ETOT * sizeof(int) + 256);
    unsigned short* h16 = (unsigned short*)p;
    p += alup((size_t)NN * HROW * sizeof(unsigned short) + 256);
    unsigned short* act16 = (unsigned short*)p;
    p += alup((size_t)NN * FF * sizeof(unsigned short) + 256);
    float* as_ = (float*)p;  p += alup(NN * sizeof(float));
    float* ad_ = (float*)p;  p += alup(NN * sizeof(float));

    hipMemsetAsync(bcnt, 0, 2048, stream);  // bcnt + bpos
    k_g0_hist<<<G0BLK + HISTBLK, 256, 0, stream>>>(x, W0, As, Ad, h16, as_, ad_, ei, bcnt);
    k_bscatter<<<(ETOT + TILE - 1) / TILE, 256, 0, stream>>>(ei, bcnt, bpos, pairs);
    k_bfill<<<NBUK, 512, 0, stream>>>(pairs, bcnt, off, ssrc);

    for (int l = 0; l < 5; l++) {
        if (l > 0) {
            int g = (NN + 255) / 256;  // R=4: 256 rows/block
            k_gemm48<<<g, 256, 0, stream>>>(act16, Wr + (size_t)(l - 1) * 48 * 48,
                                            As + l * 48, Ad + l * 48, h16, as_, ad_);
        }
        if (l == 4)
            k_aggr<true><<<(NN + 3) / 4, 256, 0, stream>>>(h16, as_, ad_, off, ssrc,
                                                           B + l * 48, out, nullptr);
        else
            k_aggr<false><<<(NN + 3) / 4, 256, 0, stream>>>(h16, as_, ad_, off, ssrc,
                                                            B + l * 48, nullptr, act16);
    }
}

// Round 21
// 407.085 us; speedup vs baseline: 1.1044x; 1.0036x over previous
//
#include <hip/hip_runtime.h>

#define NN 100000
#define EE 1600000
#define ETOT (EE + NN)
#define FF 48
#define NEG 0.2f
#define BSH 9
#define BNODES 512
#define NBUK ((NN + BNODES - 1) / BNODES)  // 196
#define TILE 2048
#define G0BLK ((NN + 127) / 128)           // 782 gemm0 blocks
#define HISTBLK 512
#define HROW 64                            // bf16 h row stride (128 B)
#define SRCMASK 0x1FFFFu                   // 17 bits

__device__ __forceinline__ unsigned short f2bf(float x) {
    unsigned u = __float_as_uint(x);
    u += 0x7FFF + ((u >> 16) & 1);         // RNE
    return (unsigned short)(u >> 16);
}
__device__ __forceinline__ float bf2f(unsigned short b) {
    return __uint_as_float(((unsigned)b) << 16);
}
__device__ __forceinline__ float bflo(unsigned u) {
    return __uint_as_float(u << 16);
}
__device__ __forceinline__ float bfhi(unsigned u) {
    return __uint_as_float(u & 0xffff0000u);
}
__device__ __forceinline__ unsigned pk(unsigned short a, unsigned short b) {
    return (unsigned)a | ((unsigned)b << 16);
}

// ---------------- GEMM + alpha body; input f32 (layer0) or bf16; h stored bf16 ----

template <int K, int KC, int R, bool IN16>
__device__ __forceinline__ void gemm_body(int bid, float* Wl, float* asl, float* adl,
                                          const void* __restrict__ inp,
                                          const float* __restrict__ W,
                                          const float* __restrict__ a_s,
                                          const float* __restrict__ a_d,
                                          unsigned short* __restrict__ h16,
                                          float* __restrict__ as_,
                                          float* __restrict__ ad_) {
    int t = threadIdx.x;
    for (int i = t; i < K * FF / 4; i += 256)
        ((float4*)Wl)[i] = ((const float4*)W)[i];
    if (t < FF) { asl[t] = a_s[t]; adl[t] = a_d[t]; }
    __syncthreads();

    int fg = t & 3;
    int pr = t >> 2;
    int r0 = bid * (64 * R) + pr * R;
    if (r0 >= NN) return;

    constexpr int NC = K / KC;
    constexpr int QC = KC / 4;
    const float4* wl4 = (const float4*)Wl;

    float acc[R][12];
#pragma unroll
    for (int r = 0; r < R; r++)
#pragma unroll
        for (int j = 0; j < 12; j++) acc[r][j] = 0.f;

    for (int c = 0; c < NC; c++) {
        float xs[R][KC];
        if (IN16) {
            const unsigned short* a16 = (const unsigned short*)inp;
#pragma unroll
            for (int r = 0; r < R; r++) {
#pragma unroll
                for (int q = 0; q < KC / 8; q++) {
                    uint4 u = *(const uint4*)(a16 + (size_t)(r0 + r) * K + c * KC + q * 8);
                    xs[r][8 * q + 0] = bflo(u.x); xs[r][8 * q + 1] = bfhi(u.x);
                    xs[r][8 * q + 2] = bflo(u.y); xs[r][8 * q + 3] = bfhi(u.y);
                    xs[r][8 * q + 4] = bflo(u.z); xs[r][8 * q + 5] = bfhi(u.z);
                    xs[r][8 * q + 6] = bflo(u.w); xs[r][8 * q + 7] = bfhi(u.w);
                }
            }
        } else {
            const float4* x4 = (const float4*)inp;
#pragma unroll
            for (int r = 0; r < R; r++) {
#pragma unroll
                for (int q = 0; q < QC; q++) {
                    float4 v = x4[(size_t)(r0 + r) * (K / 4) + c * QC + q];
                    xs[r][4 * q + 0] = v.x; xs[r][4 * q + 1] = v.y;
                    xs[r][4 * q + 2] = v.z; xs[r][4 * q + 3] = v.w;
                }
            }
        }
#pragma unroll
        for (int kk = 0; kk < KC; kk++) {
            const int k = c * KC + kk;
            const float4 w0 = wl4[k * 12 + fg * 3 + 0];
            const float4 w1 = wl4[k * 12 + fg * 3 + 1];
            const float4 w2 = wl4[k * 12 + fg * 3 + 2];
#pragma unroll
            for (int r = 0; r < R; r++) {
                const float xv = xs[r][kk];
                acc[r][0] = fmaf(xv, w0.x, acc[r][0]);
                acc[r][1] = fmaf(xv, w0.y, acc[r][1]);
                acc[r][2] = fmaf(xv, w0.z, acc[r][2]);
                acc[r][3] = fmaf(xv, w0.w, acc[r][3]);
                acc[r][4] = fmaf(xv, w1.x, acc[r][4]);
                acc[r][5] = fmaf(xv, w1.y, acc[r][5]);
                acc[r][6] = fmaf(xv, w1.z, acc[r][6]);
                acc[r][7] = fmaf(xv, w1.w, acc[r][7]);
                acc[r][8] = fmaf(xv, w2.x, acc[r][8]);
                acc[r][9] = fmaf(xv, w2.y, acc[r][9]);
                acc[r][10] = fmaf(xv, w2.z, acc[r][10]);
                acc[r][11] = fmaf(xv, w2.w, acc[r][11]);
            }
        }
    }

#pragma unroll
    for (int r = 0; r < R; r++) {
        uint2* hp = (uint2*)(h16 + (size_t)(r0 + r) * HROW + fg * 12);
        hp[0] = make_uint2(pk(f2bf(acc[r][0]), f2bf(acc[r][1])),
                           pk(f2bf(acc[r][2]), f2bf(acc[r][3])));
        hp[1] = make_uint2(pk(f2bf(acc[r][4]), f2bf(acc[r][5])),
                           pk(f2bf(acc[r][6]), f2bf(acc[r][7])));
        hp[2] = make_uint2(pk(f2bf(acc[r][8]), f2bf(acc[r][9])),
                           pk(f2bf(acc[r][10]), f2bf(acc[r][11])));
    }

    float ps[R], pd[R];
#pragma unroll
    for (int r = 0; r < R; r++) { ps[r] = 0.f; pd[r] = 0.f; }
#pragma unroll
    for (int j = 0; j < 12; j++) {
        float av = asl[fg * 12 + j], dv = adl[fg * 12 + j];
#pragma unroll
        for (int r = 0; r < R; r++) {
            ps[r] = fmaf(acc[r][j], av, ps[r]);
            pd[r] = fmaf(acc[r][j], dv, pd[r]);
        }
    }
#pragma unroll
    for (int r = 0; r < R; r++) {
        ps[r] += __shfl_xor(ps[r], 1); ps[r] += __shfl_xor(ps[r], 2);
        pd[r] += __shfl_xor(pd[r], 1); pd[r] += __shfl_xor(pd[r], 2);
    }
    if (fg == 0) {
#pragma unroll
        for (int r = 0; r < R; r++) {
            as_[r0 + r] = ps[r];
            ad_[r0 + r] = pd[r];
        }
    }
}

// merged: blocks [0, G0BLK) layer-0 gemm; [G0BLK, G0BLK+HISTBLK) bucket histogram
__global__ __launch_bounds__(256) void k_g0_hist(const float* __restrict__ x,
                                                 const float* __restrict__ W0,
                                                 const float* __restrict__ a_s,
                                                 const float* __restrict__ a_d,
                                                 unsigned short* __restrict__ h16,
                                                 float* __restrict__ as_,
                                                 float* __restrict__ ad_,
                                                 const int* __restrict__ ei,
                                                 int* __restrict__ bcnt) {
    __shared__ __align__(16) char smem[(100 * FF + 2 * FF) * 4];
    if (blockIdx.x < G0BLK) {
        float* Wl = (float*)smem;
        float* asl = Wl + 100 * FF;
        float* adl = asl + FF;
        gemm_body<100, 20, 2, false>(blockIdx.x, Wl, asl, adl, x, W0, a_s, a_d,
                                     h16, as_, ad_);
    } else {
        int* hh = (int*)smem;
        int t = threadIdx.x;
        int bid = blockIdx.x - G0BLK;
        hh[t] = 0;
        __syncthreads();
        for (int i = bid * 256 + t; i < ETOT; i += HISTBLK * 256) {
            int dd = (i < EE) ? ei[EE + i] : (i - EE);
            atomicAdd(&hh[dd >> BSH], 1);
        }
        __syncthreads();
        if (hh[t] > 0) atomicAdd(&bcnt[t], hh[t]);
    }
}

// bucketed scatter; pairs packed into one uint: src | (dst&511)<<17
__global__ __launch_bounds__(256) void k_bscatter(const int* __restrict__ ei,
                                                  const int* __restrict__ bcnt,
                                                  int* __restrict__ bpos,
                                                  unsigned* __restrict__ pairs) {
    __shared__ int hist[256], incl[256], exc[256], curv[256], gb[256], sb[256];
    __shared__ unsigned stage[TILE];
    __shared__ int staddr[TILE];
    int t = threadIdx.x;
    int bv = (t < NBUK) ? bcnt[t] : 0;
    sb[t] = bv;
    __syncthreads();
    for (int o = 1; o < 256; o <<= 1) {
        int x = (t >= o) ? sb[t - o] : 0;
        __syncthreads();
        sb[t] += x;
        __syncthreads();
    }
    int bexcl = sb[t] - bv;
    hist[t] = 0;
    __syncthreads();
    int base = blockIdx.x * TILE;
    unsigned pkd[8];
    int b[8];
#pragma unroll
    for (int j = 0; j < 8; j++) {
        int i = base + t + j * 256;
        if (i < ETOT) {
            int ss, dd;
            if (i < EE) { ss = ei[i]; dd = ei[EE + i]; }
            else { ss = i - EE; dd = ss; }
            pkd[j] = (unsigned)ss | ((unsigned)(dd & (BNODES - 1)) << 17);
            b[j] = dd >> BSH;
            atomicAdd(&hist[b[j]], 1);
        } else {
            b[j] = -1;
        }
    }
    __syncthreads();
    int hv = hist[t];
    incl[t] = hv;
    __syncthreads();
    for (int o = 1; o < 256; o <<= 1) {
        int x = (t >= o) ? incl[t - o] : 0;
        __syncthreads();
        incl[t] += x;
        __syncthreads();
    }
    int excl = incl[t] - hv;
    exc[t] = excl;
    curv[t] = excl;
    if (hv > 0) gb[t] = bexcl + atomicAdd(&bpos[t], hv);
    __syncthreads();
    int total = incl[255];
#pragma unroll
    for (int j = 0; j < 8; j++) {
        if (b[j] >= 0) {
            int pos = atomicAdd(&curv[b[j]], 1);
            stage[pos] = pkd[j];
            staddr[pos] = gb[b[j]] + (pos - exc[b[j]]);
        }
    }
    __syncthreads();
    for (int i = t; i < total; i += 256) pairs[staddr[i]] = stage[i];
}

// one block (512 threads) per bucket; unpack dl = pr>>17, src = pr & 0x1FFFF
__global__ __launch_bounds__(512) void k_bfill(const unsigned* __restrict__ pairs,
                                               const int* __restrict__ bcnt,
                                               int* __restrict__ off,
                                               int* __restrict__ ssrc) {
    __shared__ int cnt[BNODES], cu[BNODES], sb[512];
    int blk = blockIdx.x;
    int t = threadIdx.x;
    int n0 = blk << BSH;
    int bv = (t < NBUK) ? bcnt[t] : 0;
    sb[t] = bv;
    __syncthreads();
    for (int o = 1; o < 512; o <<= 1) {
        int x = (t >= o) ? sb[t - o] : 0;
        __syncthreads();
        sb[t] += x;
        __syncthreads();
    }
    int beg = sb[blk] - bcnt[blk];
    int end = sb[blk];
    __syncthreads();
    cnt[t] = 0;
    __syncthreads();
    for (int i = beg + t; i < end; i += 512) {
        atomicAdd(&cnt[pairs[i] >> 17], 1);
    }
    __syncthreads();
    int v = cnt[t];
    sb[t] = v;
    __syncthreads();
    for (int o = 1; o < 512; o <<= 1) {
        int x = (t >= o) ? sb[t - o] : 0;
        __syncthreads();
        sb[t] += x;
        __syncthreads();
    }
    int excl = sb[t] - v;
    cu[t] = excl;
    if (n0 + t < NN) off[n0 + t] = beg + excl;
    if (blk == 0 && t == 0) off[NN] = ETOT;
    __syncthreads();
    for (int i = beg + t; i < end; i += 512) {
        unsigned pr = pairs[i];
        int pos = atomicAdd(&cu[pr >> 17], 1);
        ssrc[beg + pos] = (int)(pr & SRCMASK);
    }
}

// standalone K=48 gemm (R=4), bf16 input
__global__ __launch_bounds__(256) void k_gemm48(const unsigned short* __restrict__ a16,
                                                const float* __restrict__ W,
                                                const float* __restrict__ a_s,
                                                const float* __restrict__ a_d,
                                                unsigned short* __restrict__ h16,
                                                float* __restrict__ as_,
                                                float* __restrict__ ad_) {
    __shared__ float Wl[48 * FF];
    __shared__ float asl[FF], adl[FF];
    gemm_body<48, 16, 4, true>(blockIdx.x, Wl, asl, adl, a16, W, a_s, a_d,
                               h16, as_, ad_);
}

// ---------------- aggregation (R20-identical) ----------------

template <bool LAST>
__global__ __launch_bounds__(256) void k_aggr(const unsigned short* __restrict__ h16,
                                              const float* __restrict__ as_,
                                              const float* __restrict__ ad_,
                                              const int* __restrict__ off,
                                              const int* __restrict__ ssrc,
                                              const float* __restrict__ bias,
                                              float* __restrict__ out,
                                              unsigned short* __restrict__ act16) {
    int wave = threadIdx.x >> 6;
    int lane = threadIdx.x & 63;
    int d = blockIdx.x * 4 + wave;
    if (d >= NN) return;
    int beg = __builtin_amdgcn_readfirstlane(off[d]);
    int end = __builtin_amdgcn_readfirstlane(off[d + 1]);
    int deg = end - beg;
    float add = ad_[d];
    int fW = (lane < FF) ? lane : lane - FF;
    unsigned foff = (unsigned)(fW * 2);
    const char* hb = (const char*)h16;

    float acc = 0.f, s = 0.f;

    if (deg <= 64) {
        int srcb = 0;
        float e = -1e30f;
        if (lane < deg) {
            int src = ssrc[beg + lane];
            srcb = src << 7;               // 128 B rows
            float t = as_[src] + add;
            e = (t > 0.f) ? t : NEG * t;
        }
        float m = e;
#pragma unroll
        for (int o = 32; o; o >>= 1) m = fmaxf(m, __shfl_xor(m, o));
        float p = (lane < deg) ? __expf(e - m) : 0.f;
        float sv = p;
#pragma unroll
        for (int o = 32; o; o >>= 1) sv += __shfl_xor(sv, o);
        s = sv;

        unsigned pbits = __float_as_uint(p);
        int degR = (deg + 7) & ~7;
        for (int i = 0; i < degR; i += 8) {
            float pj[8], hv[8];
#pragma unroll
            for (int j = 0; j < 8; j++) {
                pj[j] = __uint_as_float(
                    (unsigned)__builtin_amdgcn_readlane((int)pbits, i + j));
                int sbj = __builtin_amdgcn_readlane(srcb, i + j);
                hv[j] = bf2f(*(const unsigned short*)(hb + (unsigned)sbj + foff));
            }
#pragma unroll
            for (int j = 0; j < 8; j++) acc = fmaf(pj[j], hv[j], acc);
        }
    } else {
        // general path (never taken for this graph)
        float m = -1e30f;
        for (int i = beg + lane; i < end; i += 64) {
            float t = as_[ssrc[i]] + add;
            t = (t > 0.f) ? t : NEG * t;
            m = fmaxf(m, t);
        }
#pragma unroll
        for (int o = 32; o; o >>= 1) m = fmaxf(m, __shfl_xor(m, o));
        for (int i = beg; i < end; i++) {
            int src = ssrc[i];
            float e = as_[src] + add;
            e = (e > 0.f) ? e : NEG * e;
            float pp = __expf(e - m);
            s += pp;
            if (lane < FF) acc = fmaf(pp, bf2f(h16[(size_t)src * HROW + lane]), acc);
        }
    }

    if (lane < FF) {
        float v = acc / fmaxf(s, 1e-16f) + bias[lane];
        v = (v > 0.f) ? v : (__expf(v) - 1.0f);  // ELU
        if (LAST)
            out[(size_t)d * FF + lane] = v;
        else
            act16[(size_t)d * FF + lane] = f2bf(v);
    }
}

// ---------------- launcher ----------------

static inline size_t alup(size_t x) { return (x + 255) & ~(size_t)255; }

extern "C" void kernel_launch(void* const* d_in, const int* in_sizes, int n_in,
                              void* d_out, int out_size, void* d_ws, size_t ws_size,
                              hipStream_t stream) {
    const float* x = (const float*)d_in[0];
    const int* ei = (const int*)d_in[1];
    const float* W0 = (const float*)d_in[2];
    const float* Wr = (const float*)d_in[3];
    const float* As = (const float*)d_in[4];
    const float* Ad = (const float*)d_in[5];
    const float* B = (const float*)d_in[6];
    float* out = (float*)d_out;

    char* p = (char*)d_ws;
    int* off = (int*)p;       p += alup((NN + 1) * sizeof(int));
    int* bcnt = (int*)p;      p += 1024;
    int* bpos = (int*)p;      p += 1024;
    unsigned* pairs = (unsigned*)p; p += alup((size_t)ETOT * sizeof(unsigned));
    int* ssrc = (int*)p;      p += alup((size_t)ETOT * sizeof(int) + 256);
    unsigned short* h16 = (unsigned short*)p;
    p += alup((size_t)NN * HROW * sizeof(unsigned short) + 256);
    unsigned short* act16 = (unsigned short*)p;
    p += alup((size_t)NN * FF * sizeof(unsigned short) + 256);
    float* as_ = (float*)p;   p += alup(NN * sizeof(float));
    float* ad_ = (float*)p;   p += alup(NN * sizeof(float));

    hipMemsetAsync(bcnt, 0, 2048, stream);  // bcnt + bpos
    k_g0_hist<<<G0BLK + HISTBLK, 256, 0, stream>>>(x, W0, As, Ad, h16, as_, ad_, ei, bcnt);
    k_bscatter<<<(ETOT + TILE - 1) / TILE, 256, 0, stream>>>(ei, bcnt, bpos, pairs);
    k_bfill<<<NBUK, 512, 0, stream>>>(pairs, bcnt, off, ssrc);

    for (int l = 0; l < 5; l++) {
        if (l > 0) {
            int g = (NN + 255) / 256;  // R=4: 256 rows/block
            k_gemm48<<<g, 256, 0, stream>>>(act16, Wr + (size_t)(l - 1) * 48 * 48,
                                            As + l * 48, Ad + l * 48, h16, as_, ad_);
        }
        if (l == 4)
            k_aggr<true><<<(NN + 3) / 4, 256, 0, stream>>>(h16, as_, ad_, off, ssrc,
                                                           B + l * 48, out, nullptr);
        else
            k_aggr<false><<<(NN + 3) / 4, 256, 0, stream>>>(h16, as_, ad_, off, ssrc,
                                                            B + l * 48, nullptr, act16);
    }
}